// Round 1
// baseline (24.370 us; speedup 1.0000x reference)
//
#include <hip/hip_runtime.h>

// SegmentationLoss: scalar = sum_{b,l,i} g[b,l,i] * sqrt(sum_f (p[b,l,f]-g[b,l,i])^2)
// Shapes: input (8,16,256,256) f32, target (8,8,256,256) f32, out: 1 f32.
// Identity: sum_f (p_f - g)^2 = s2 - 2 g s1 + NF g^2  with s1=sum p_f, s2=sum p_f^2.

#define HW   (256 * 256)
#define NF   16
#define NI   8
#define BSZ  8

__global__ __launch_bounds__(256) void seg_loss_kernel(const float* __restrict__ input,
                                                       const float* __restrict__ target,
                                                       float* __restrict__ out) {
    const int tid  = blockIdx.x * blockDim.x + threadIdx.x;   // 0 .. BSZ*HW/4 - 1
    const int loc0 = tid << 2;                                // 4 consecutive locations
    const int b    = loc0 >> 16;                              // / HW
    const int l    = loc0 & (HW - 1);

    const float4* ip = reinterpret_cast<const float4*>(input  + (size_t)b * NF * HW + l);
    const float4* tp = reinterpret_cast<const float4*>(target + (size_t)b * NI * HW + l);

    float4 s1 = make_float4(0.f, 0.f, 0.f, 0.f);
    float4 s2 = make_float4(0.f, 0.f, 0.f, 0.f);
#pragma unroll
    for (int f = 0; f < NF; ++f) {
        float4 p = ip[f * (HW / 4)];
        s1.x += p.x; s1.y += p.y; s1.z += p.z; s1.w += p.w;
        s2.x += p.x * p.x; s2.y += p.y * p.y; s2.z += p.z * p.z; s2.w += p.w * p.w;
    }

    float acc = 0.f;
#pragma unroll
    for (int i = 0; i < NI; ++i) {
        float4 g = tp[i * (HW / 4)];
        acc += g.x * sqrtf(fmaxf(s2.x - 2.f * g.x * s1.x + (float)NF * g.x * g.x, 0.f));
        acc += g.y * sqrtf(fmaxf(s2.y - 2.f * g.y * s1.y + (float)NF * g.y * g.y, 0.f));
        acc += g.z * sqrtf(fmaxf(s2.z - 2.f * g.z * s1.z + (float)NF * g.z * g.z, 0.f));
        acc += g.w * sqrtf(fmaxf(s2.w - 2.f * g.w * s1.w + (float)NF * g.w * g.w, 0.f));
    }

    // Wave (64-lane) shuffle reduction
#pragma unroll
    for (int off = 32; off > 0; off >>= 1)
        acc += __shfl_down(acc, off, 64);

    __shared__ float wsum[4];
    const int lane = threadIdx.x & 63;
    const int wid  = threadIdx.x >> 6;
    if (lane == 0) wsum[wid] = acc;
    __syncthreads();
    if (threadIdx.x == 0) {
        float s = wsum[0] + wsum[1] + wsum[2] + wsum[3];
        atomicAdd(out, s);
    }
}

extern "C" void kernel_launch(void* const* d_in, const int* in_sizes, int n_in,
                              void* d_out, int out_size, void* d_ws, size_t ws_size,
                              hipStream_t stream) {
    const float* input  = (const float*)d_in[0];
    const float* target = (const float*)d_in[1];
    float* out = (float*)d_out;

    hipMemsetAsync(out, 0, sizeof(float), stream);

    const int total_threads = BSZ * HW / 4;   // 131072
    const int block = 256;
    const int grid  = total_threads / block;  // 512
    seg_loss_kernel<<<grid, block, 0, stream>>>(input, target, out);
}